// Round 1
// baseline (198.913 us; speedup 1.0000x reference)
//
#include <hip/hip_runtime.h>

#define EMBED 8
#define FFN_DIM 2048
#define LN_EPS 1e-5f

__global__ __launch_bounds__(256) void tbq_kernel(
    const float* __restrict__ x,
    const float* __restrict__ Wq,
    const float* __restrict__ Wo,
    const float* __restrict__ W1,
    const float* __restrict__ b1,
    const float* __restrict__ W2,
    const float* __restrict__ b2,
    const float* __restrict__ g1,
    const float* __restrict__ beta1,
    const float* __restrict__ g2,
    const float* __restrict__ beta2,
    float* __restrict__ out,
    int ntok)
{
    const int t = blockIdx.x * blockDim.x + threadIdx.x;
    if (t >= ntok) return;

    // ---- load x row: 8 floats = 2 x float4 (coalesced 32B/lane) ----
    const float4* xr = reinterpret_cast<const float4*>(x + (size_t)t * EMBED);
    float4 xa = xr[0], xb = xr[1];
    float xv[EMBED] = {xa.x, xa.y, xa.z, xa.w, xb.x, xb.y, xb.z, xb.w};

    // ---- q = x @ Wq^T, qm = cumprod(cos(q)) ----
    float qm[EMBED];
    {
        float c = 1.0f;
        #pragma unroll
        for (int f = 0; f < EMBED; ++f) {
            float acc = 0.0f;
            #pragma unroll
            for (int e = 0; e < EMBED; ++e) acc += xv[e] * Wq[f * EMBED + e];
            c *= __cosf(acc);
            qm[f] = c;
        }
    }

    // ---- attn = qm @ Wo^T ; h = LN(x + attn) * g1 + beta1 ----
    float h[EMBED];
    float mu = 0.0f;
    #pragma unroll
    for (int f = 0; f < EMBED; ++f) {
        float acc = 0.0f;
        #pragma unroll
        for (int e = 0; e < EMBED; ++e) acc += qm[e] * Wo[f * EMBED + e];
        h[f] = xv[f] + acc;
        mu += h[f];
    }
    mu *= 0.125f;
    float var = 0.0f;
    #pragma unroll
    for (int i = 0; i < EMBED; ++i) { float d = h[i] - mu; var += d * d; }
    var *= 0.125f;
    float rs = rsqrtf(var + LN_EPS);
    #pragma unroll
    for (int i = 0; i < EMBED; ++i) h[i] = (h[i] - mu) * rs * g1[i] + beta1[i];

    // ---- m = cumprod(cos(h)) ----
    float m[EMBED];
    {
        float c = 1.0f;
        #pragma unroll
        for (int i = 0; i < EMBED; ++i) { c *= __cosf(h[i]); m[i] = c; }
    }

    // ---- FFN: hid = relu(m @ W1^T + b1); ffn = hid @ W2^T + b2 ----
    float ffn[EMBED];
    #pragma unroll
    for (int e = 0; e < EMBED; ++e) ffn[e] = b2[e];

    // f-loop: weights indexed by (uniform f) -> scalar loads into SGPRs.
    // unroll 4: 4 independent hid chains (hide FMA latency), 8 indep ffn accs.
    #pragma unroll 4
    for (int f = 0; f < FFN_DIM; ++f) {
        float acc = b1[f];
        #pragma unroll
        for (int e = 0; e < EMBED; ++e) acc += m[e] * W1[f * EMBED + e];
        acc = fmaxf(acc, 0.0f);
        #pragma unroll
        for (int e = 0; e < EMBED; ++e) ffn[e] += acc * W2[e * FFN_DIM + f];
    }

    // ---- out = LN(h + ffn) * g2 + beta2 ----
    float o[EMBED];
    float mu2 = 0.0f;
    #pragma unroll
    for (int i = 0; i < EMBED; ++i) { o[i] = h[i] + ffn[i]; mu2 += o[i]; }
    mu2 *= 0.125f;
    float v2 = 0.0f;
    #pragma unroll
    for (int i = 0; i < EMBED; ++i) { float d = o[i] - mu2; v2 += d * d; }
    v2 *= 0.125f;
    float rs2 = rsqrtf(v2 + LN_EPS);

    float res[EMBED];
    #pragma unroll
    for (int i = 0; i < EMBED; ++i) res[i] = (o[i] - mu2) * rs2 * g2[i] + beta2[i];

    float4* orow = reinterpret_cast<float4*>(out + (size_t)t * EMBED);
    orow[0] = make_float4(res[0], res[1], res[2], res[3]);
    orow[1] = make_float4(res[4], res[5], res[6], res[7]);
}

extern "C" void kernel_launch(void* const* d_in, const int* in_sizes, int n_in,
                              void* d_out, int out_size, void* d_ws, size_t ws_size,
                              hipStream_t stream) {
    const float* x     = (const float*)d_in[0];
    const float* Wq    = (const float*)d_in[1];
    const float* Wo    = (const float*)d_in[2];
    const float* W1    = (const float*)d_in[3];
    const float* b1    = (const float*)d_in[4];
    const float* W2    = (const float*)d_in[5];
    const float* b2    = (const float*)d_in[6];
    const float* g1    = (const float*)d_in[7];
    const float* beta1 = (const float*)d_in[8];
    const float* g2    = (const float*)d_in[9];
    const float* beta2 = (const float*)d_in[10];
    float* out = (float*)d_out;

    const int ntok = in_sizes[0] / EMBED;      // 131072
    const int block = 256;
    const int grid = (ntok + block - 1) / block;

    tbq_kernel<<<grid, block, 0, stream>>>(x, Wq, Wo, W1, b1, W2, b2,
                                           g1, beta1, g2, beta2, out, ntok);
}

// Round 2
// 147.876 us; speedup vs baseline: 1.3451x; 1.3451x over previous
//
#include <hip/hip_runtime.h>

#define EMBED 8
#define FFN_DIM 2048
#define LN_EPS 1e-5f
#define TOK_PER_BLK 64
#define NSPLIT 4
#define F_PER (FFN_DIM / NSPLIT)   // 512 f-values per wave

__global__ __launch_bounds__(256) void tbq_kernel(
    const float* __restrict__ x,
    const float* __restrict__ Wq,
    const float* __restrict__ Wo,
    const float* __restrict__ W1,
    const float* __restrict__ b1,
    const float* __restrict__ W2,
    const float* __restrict__ b2,
    const float* __restrict__ g1,
    const float* __restrict__ beta1,
    const float* __restrict__ g2,
    const float* __restrict__ beta2,
    float* __restrict__ out)
{
    // part[w][tok][e]: per-wave partial ffn sums
    __shared__ float part[NSPLIT][TOK_PER_BLK][EMBED];

    const int lane = threadIdx.x & 63;
    const int w    = __builtin_amdgcn_readfirstlane(threadIdx.x >> 6); // wave id 0..3 (SGPR)
    const int t    = blockIdx.x * TOK_PER_BLK + lane;                  // token id

    // ---- load x row: 8 floats = 2 x float4 ----
    const float4* xr = reinterpret_cast<const float4*>(x + (size_t)t * EMBED);
    float4 xa = xr[0], xb = xr[1];
    float xv[EMBED] = {xa.x, xa.y, xa.z, xa.w, xb.x, xb.y, xb.z, xb.w};

    // ---- prefix (duplicated across the 4 waves; ~3% of work) ----
    // q = x @ Wq^T ; qm = cumprod(cos(q))
    float qm[EMBED];
    {
        float c = 1.0f;
        #pragma unroll
        for (int f = 0; f < EMBED; ++f) {
            float acc = 0.0f;
            #pragma unroll
            for (int e = 0; e < EMBED; ++e) acc += xv[e] * Wq[f * EMBED + e];
            c *= __cosf(acc);
            qm[f] = c;
        }
    }

    // attn = qm @ Wo^T ; h = LN(x + attn) * g1 + beta1
    float h[EMBED];
    float mu = 0.0f;
    #pragma unroll
    for (int f = 0; f < EMBED; ++f) {
        float acc = 0.0f;
        #pragma unroll
        for (int e = 0; e < EMBED; ++e) acc += qm[e] * Wo[f * EMBED + e];
        h[f] = xv[f] + acc;
        mu += h[f];
    }
    mu *= 0.125f;
    float var = 0.0f;
    #pragma unroll
    for (int i = 0; i < EMBED; ++i) { float d = h[i] - mu; var += d * d; }
    var *= 0.125f;
    float rs = rsqrtf(var + LN_EPS);
    #pragma unroll
    for (int i = 0; i < EMBED; ++i) h[i] = (h[i] - mu) * rs * g1[i] + beta1[i];

    // m = cumprod(cos(h))
    float m[EMBED];
    {
        float c = 1.0f;
        #pragma unroll
        for (int i = 0; i < EMBED; ++i) { c *= __cosf(h[i]); m[i] = c; }
    }

    // ---- FFN partial over this wave's f-range (weights stay SGPR-uniform) ----
    float ffn[EMBED];
    #pragma unroll
    for (int e = 0; e < EMBED; ++e) ffn[e] = 0.0f;

    const float* W1w = W1 + (size_t)w * F_PER * EMBED;   // wave-uniform base
    const float* b1w = b1 + (size_t)w * F_PER;
    const float* W2w = W2 + (size_t)w * F_PER;           // column offset

    #pragma unroll 4
    for (int i = 0; i < F_PER; ++i) {
        float acc = b1w[i];
        #pragma unroll
        for (int e = 0; e < EMBED; ++e) acc += m[e] * W1w[i * EMBED + e];
        acc = fmaxf(acc, 0.0f);
        #pragma unroll
        for (int e = 0; e < EMBED; ++e) ffn[e] += acc * W2w[e * FFN_DIM + i];
    }

    #pragma unroll
    for (int e = 0; e < EMBED; ++e) part[w][lane][e] = ffn[e];
    __syncthreads();

    // ---- wave 0 finalizes: reduce partials, LN2, store ----
    if (w == 0) {
        float o[EMBED];
        float mu2 = 0.0f;
        #pragma unroll
        for (int e = 0; e < EMBED; ++e) {
            float s = part[0][lane][e] + part[1][lane][e]
                    + part[2][lane][e] + part[3][lane][e] + b2[e];
            o[e] = h[e] + s;
            mu2 += o[e];
        }
        mu2 *= 0.125f;
        float v2 = 0.0f;
        #pragma unroll
        for (int e = 0; e < EMBED; ++e) { float d = o[e] - mu2; v2 += d * d; }
        v2 *= 0.125f;
        float rs2 = rsqrtf(v2 + LN_EPS);

        float res[EMBED];
        #pragma unroll
        for (int e = 0; e < EMBED; ++e) res[e] = (o[e] - mu2) * rs2 * g2[e] + beta2[e];

        float4* orow = reinterpret_cast<float4*>(out + (size_t)t * EMBED);
        orow[0] = make_float4(res[0], res[1], res[2], res[3]);
        orow[1] = make_float4(res[4], res[5], res[6], res[7]);
    }
}

extern "C" void kernel_launch(void* const* d_in, const int* in_sizes, int n_in,
                              void* d_out, int out_size, void* d_ws, size_t ws_size,
                              hipStream_t stream) {
    const float* x     = (const float*)d_in[0];
    const float* Wq    = (const float*)d_in[1];
    const float* Wo    = (const float*)d_in[2];
    const float* W1    = (const float*)d_in[3];
    const float* b1    = (const float*)d_in[4];
    const float* W2    = (const float*)d_in[5];
    const float* b2    = (const float*)d_in[6];
    const float* g1    = (const float*)d_in[7];
    const float* beta1 = (const float*)d_in[8];
    const float* g2    = (const float*)d_in[9];
    const float* beta2 = (const float*)d_in[10];
    float* out = (float*)d_out;

    const int ntok = in_sizes[0] / EMBED;           // 131072
    const int grid = ntok / TOK_PER_BLK;            // 2048 blocks
    tbq_kernel<<<grid, 256, 0, stream>>>(x, Wq, Wo, W1, b1, W2, b2,
                                         g1, beta1, g2, beta2, out);
}

// Round 3
// 61.085 us; speedup vs baseline: 3.2564x; 2.4208x over previous
//
#include <hip/hip_runtime.h>
#include <hip/hip_bf16.h>

#define FFN 2048
#define LN_EPS 1e-5f
#define W2P 2056   // padded row stride (ushorts) for W2c: breaks 4096B-stride bank conflicts

typedef __attribute__((ext_vector_type(8))) short bf16x8;
typedef __attribute__((ext_vector_type(4))) float f32x4;

union FragU { bf16x8 v; unsigned u[4]; };

static __device__ __forceinline__ unsigned pk2(float a, float b) {
    union { __hip_bfloat162 h; unsigned u; } cv;
    cv.h = __float22bfloat162_rn(make_float2(a, b));
    return cv.u;
}

__global__ __launch_bounds__(256) void tbq_mfma(
    const float* __restrict__ x,
    const float* __restrict__ Wq,
    const float* __restrict__ Wo,
    const float* __restrict__ W1,
    const float* __restrict__ b1,
    const float* __restrict__ W2,
    const float* __restrict__ b2,
    const float* __restrict__ g1,
    const float* __restrict__ beta1,
    const float* __restrict__ g2,
    const float* __restrict__ beta2,
    float* __restrict__ out)
{
    __shared__ __align__(16) ushort W1c[FFN * 8];    // 32KB  [f][e] bf16
    __shared__ __align__(16) ushort W2c[8 * W2P];    // ~32.9KB [e][f+pad] bf16
    __shared__ __align__(16) ushort b1c[FFN];        // 4KB
    __shared__ __align__(16) float  oS[256 * 8];     // 8KB; first 4KB doubles as m-scratch

    const int tid  = threadIdx.x;
    const int lane = tid & 63;
    const int wv   = tid >> 6;
    const int c    = lane & 15;     // MFMA col / A-row index
    const int g    = lane >> 4;     // MFMA 16-lane group

    // ---------- stage weights to LDS as bf16 ----------
    {
        const float4* w1 = (const float4*)W1;
        unsigned* d1 = (unsigned*)W1c;
        #pragma unroll
        for (int i = 0; i < 16; ++i) {
            int idx = i * 256 + tid;                 // 4096 float4s
            float4 v = w1[idx];
            d1[idx * 2]     = pk2(v.x, v.y);
            d1[idx * 2 + 1] = pk2(v.z, v.w);
        }
        const float4* w2 = (const float4*)W2;
        #pragma unroll
        for (int i = 0; i < 16; ++i) {
            int idx = i * 256 + tid;
            float4 v = w2[idx];
            int f = (idx * 4) & (FFN - 1);
            int e = (idx * 4) >> 11;
            unsigned* row = (unsigned*)&W2c[e * W2P + f];
            row[0] = pk2(v.x, v.y);
            row[1] = pk2(v.z, v.w);
        }
        const float4* bb = (const float4*)b1;
        unsigned* db = (unsigned*)b1c;
        #pragma unroll
        for (int i = 0; i < 2; ++i) {
            int idx = i * 256 + tid;                 // 512 float4s
            float4 v = bb[idx];
            db[idx * 2]     = pk2(v.x, v.y);
            db[idx * 2 + 1] = pk2(v.z, v.w);
        }
    }
    __syncthreads();

    // ---------- per-lane prefix: token t ----------
    const int t = blockIdx.x * 256 + tid;
    const float4* xr = (const float4*)(x + (size_t)t * 8);
    float4 xa = xr[0], xb = xr[1];
    float xv[8] = {xa.x, xa.y, xa.z, xa.w, xb.x, xb.y, xb.z, xb.w};

    float qm[8];
    {
        float cp = 1.0f;
        #pragma unroll
        for (int f = 0; f < 8; ++f) {
            float acc = 0.0f;
            #pragma unroll
            for (int e = 0; e < 8; ++e) acc += xv[e] * Wq[f * 8 + e];
            cp *= __cosf(acc);
            qm[f] = cp;
        }
    }
    float h[8];
    float mu = 0.0f;
    #pragma unroll
    for (int f = 0; f < 8; ++f) {
        float acc = 0.0f;
        #pragma unroll
        for (int e = 0; e < 8; ++e) acc += qm[e] * Wo[f * 8 + e];
        h[f] = xv[f] + acc;
        mu += h[f];
    }
    mu *= 0.125f;
    float var = 0.0f;
    #pragma unroll
    for (int i = 0; i < 8; ++i) { float d = h[i] - mu; var += d * d; }
    var *= 0.125f;
    float rs = rsqrtf(var + LN_EPS);
    #pragma unroll
    for (int i = 0; i < 8; ++i) h[i] = (h[i] - mu) * rs * g1[i] + beta1[i];

    float m[8];
    {
        float cp = 1.0f;
        #pragma unroll
        for (int i = 0; i < 8; ++i) { cp *= __cosf(h[i]); m[i] = cp; }
    }

    // ---------- scatter m (bf16) and gather B1 fragments (m^T, ones-row aug) ----------
    {
        uint4 mq;
        mq.x = pk2(m[0], m[1]); mq.y = pk2(m[2], m[3]);
        mq.z = pk2(m[4], m[5]); mq.w = pk2(m[6], m[7]);
        ((uint4*)oS)[tid] = mq;            // bytes tid*16 < 4096
    }
    asm volatile("s_waitcnt lgkmcnt(0)" ::: "memory");

    FragU B1[4];
    #pragma unroll
    for (int T = 0; T < 4; ++T) {
        uint4 mr = ((const uint4*)oS)[wv * 64 + T * 16 + c];
        B1[T].u[0] = (g == 0) ? mr.x : ((g == 1) ? 0x00003F80u : 0u); // k=8 row: 1.0bf16
        B1[T].u[1] = (g == 0) ? mr.y : 0u;
        B1[T].u[2] = (g == 0) ? mr.z : 0u;
        B1[T].u[3] = (g == 0) ? mr.w : 0u;
    }
    __syncthreads();   // all B1 reads done -> oS reusable for epilogue

    // ---------- fused FFN: 64 chunks of 32 f-values ----------
    f32x4 acc[4] = {{0,0,0,0},{0,0,0,0},{0,0,0,0},{0,0,0,0}};
    const bool g0 = (g == 0), g1m = (g == 1), ev = (c < 8);
    const int e7 = lane & 7;

    #pragma unroll 2
    for (int cc = 0; cc < 64; ++cc) {
        const int fb = cc * 32;
        // W1aug A-fragments (rows=f, k=e 0..7 + bias at k=8)
        uint4 wA = ((const uint4*)W1c)[fb + c];
        uint4 wB = ((const uint4*)W1c)[fb + 16 + c];
        unsigned bb0 = b1c[fb + c];
        unsigned bb1 = b1c[fb + 16 + c];
        FragU F0, F1;
        F0.u[0] = g0 ? wA.x : (g1m ? bb0 : 0u);
        F0.u[1] = g0 ? wA.y : 0u; F0.u[2] = g0 ? wA.z : 0u; F0.u[3] = g0 ? wA.w : 0u;
        F1.u[0] = g0 ? wB.x : (g1m ? bb1 : 0u);
        F1.u[1] = g0 ? wB.y : 0u; F1.u[2] = g0 ? wB.z : 0u; F1.u[3] = g0 ? wB.w : 0u;

        // W2 A-fragment, permuted k-order: k=8g+j <-> f = fb + 4g + (j&3) + 16*(j>>2)
        const ushort* wr = &W2c[e7 * W2P + fb + 4 * g];
        unsigned long long lo = *(const unsigned long long*)wr;
        unsigned long long hi = *(const unsigned long long*)(wr + 16);
        FragU A2;
        A2.u[0] = ev ? (unsigned)lo        : 0u;
        A2.u[1] = ev ? (unsigned)(lo >> 32) : 0u;
        A2.u[2] = ev ? (unsigned)hi        : 0u;
        A2.u[3] = ev ? (unsigned)(hi >> 32) : 0u;

        #pragma unroll
        for (int T = 0; T < 4; ++T) {
            f32x4 z = {0, 0, 0, 0};
            f32x4 c0 = __builtin_amdgcn_mfma_f32_16x16x32_bf16(F0.v, B1[T].v, z, 0, 0, 0);
            f32x4 c1 = __builtin_amdgcn_mfma_f32_16x16x32_bf16(F1.v, B1[T].v, z, 0, 0, 0);
            // hid = relu(.); C-frag rows (4g..4g+3) of f-tiles -> B2 frag, no lane moves
            FragU B2;
            B2.u[0] = pk2(fmaxf(c0[0], 0.f), fmaxf(c0[1], 0.f));
            B2.u[1] = pk2(fmaxf(c0[2], 0.f), fmaxf(c0[3], 0.f));
            B2.u[2] = pk2(fmaxf(c1[0], 0.f), fmaxf(c1[1], 0.f));
            B2.u[3] = pk2(fmaxf(c1[2], 0.f), fmaxf(c1[3], 0.f));
            acc[T] = __builtin_amdgcn_mfma_f32_16x16x32_bf16(A2.v, B2.v, acc[T], 0, 0, 0);
        }
    }

    // ---------- epilogue: out^T frags -> oS, per-lane LN2, store ----------
    if (g < 2) {
        #pragma unroll
        for (int T = 0; T < 4; ++T) {
            int tok = wv * 64 + T * 16 + c;
            *(f32x4*)&oS[tok * 8 + 4 * g] = acc[T];
        }
    }
    asm volatile("s_waitcnt lgkmcnt(0)" ::: "memory");

    f32x4 p0 = ((const f32x4*)oS)[tid * 2];
    f32x4 p1 = ((const f32x4*)oS)[tid * 2 + 1];
    float ffnv[8] = {p0[0], p0[1], p0[2], p0[3], p1[0], p1[1], p1[2], p1[3]};

    float o[8];
    float mu2 = 0.0f;
    #pragma unroll
    for (int i = 0; i < 8; ++i) { o[i] = h[i] + ffnv[i] + b2[i]; mu2 += o[i]; }
    mu2 *= 0.125f;
    float v2 = 0.0f;
    #pragma unroll
    for (int i = 0; i < 8; ++i) { float d = o[i] - mu2; v2 += d * d; }
    v2 *= 0.125f;
    float rs2 = rsqrtf(v2 + LN_EPS);

    float res[8];
    #pragma unroll
    for (int i = 0; i < 8; ++i) res[i] = (o[i] - mu2) * rs2 * g2[i] + beta2[i];

    float4* orow = (float4*)(out + (size_t)t * 8);
    orow[0] = make_float4(res[0], res[1], res[2], res[3]);
    orow[1] = make_float4(res[4], res[5], res[6], res[7]);
}

extern "C" void kernel_launch(void* const* d_in, const int* in_sizes, int n_in,
                              void* d_out, int out_size, void* d_ws, size_t ws_size,
                              hipStream_t stream) {
    const float* x     = (const float*)d_in[0];
    const float* Wq    = (const float*)d_in[1];
    const float* Wo    = (const float*)d_in[2];
    const float* W1    = (const float*)d_in[3];
    const float* b1    = (const float*)d_in[4];
    const float* W2    = (const float*)d_in[5];
    const float* b2    = (const float*)d_in[6];
    const float* g1    = (const float*)d_in[7];
    const float* beta1 = (const float*)d_in[8];
    const float* g2    = (const float*)d_in[9];
    const float* beta2 = (const float*)d_in[10];
    float* out = (float*)d_out;

    const int ntok = in_sizes[0] / 8;      // 131072
    const int grid = ntok / 256;           // 512 blocks x 4 waves x 64 tok
    tbq_mfma<<<grid, 256, 0, stream>>>(x, Wq, Wo, W1, b1, W2, b2,
                                       g1, beta1, g2, beta2, out);
}

// Round 4
// 52.237 us; speedup vs baseline: 3.8079x; 1.1694x over previous
//
#include <hip/hip_runtime.h>
#include <hip/hip_bf16.h>

#define FFN 2048
#define LN_EPS 1e-5f

typedef __attribute__((ext_vector_type(8))) short bf16x8;
typedef __attribute__((ext_vector_type(4))) float f32x4;

union FragU { bf16x8 v; unsigned u[4]; uint4 q; };

static __device__ __forceinline__ unsigned cvtpk(float lo, float hi) {
    unsigned r;
    asm("v_cvt_pk_bf16_f32 %0, %1, %2" : "=v"(r) : "v"(lo), "v"(hi));
    return r;
}

static __device__ __forceinline__ ushort to_bf16(float f) {   // RNE, finite inputs
    unsigned u = __float_as_uint(f);
    u += 0x7fffu + ((u >> 16) & 1u);
    return (ushort)(u >> 16);
}

// ---------------- prep: bake exact per-lane MFMA fragments into ws ----------------
// ws uint4 layout: [0..8191]  fragW1[cc][s][lane]  (A-frag of W1aug: k=8g+j, k<8 -> W1[f][k],
//                                                   k==8 -> b1[f], else 0; f = cc*32+s*16+c)
//                  [8192..12287] fragW2[cc][lane]  (A-frag of W2, permuted k: lane(c,g), j ->
//                                                   f_local = 4g + (j&3) + 16*(j>>2); rows c>=8 zero)
__global__ __launch_bounds__(256) void tbq_prep(
    const float* __restrict__ W1, const float* __restrict__ b1,
    const float* __restrict__ W2, uint4* __restrict__ ws)
{
    const int idx = blockIdx.x * 256 + threadIdx.x;
    ushort v[8] = {0,0,0,0,0,0,0,0};
    if (idx < 8192) {
        const int lane = idx & 63, s = (idx >> 6) & 1, cc = idx >> 7;
        const int c = lane & 15, g = lane >> 4;
        const int f = cc * 32 + s * 16 + c;
        if (g == 0) {
            #pragma unroll
            for (int j = 0; j < 8; ++j) v[j] = to_bf16(W1[f * 8 + j]);
        } else if (g == 1) {
            v[0] = to_bf16(b1[f]);
        }
    } else {
        const int i2 = idx - 8192;
        const int lane = i2 & 63, cc = i2 >> 6;
        const int c = lane & 15, g = lane >> 4;
        if (c < 8) {
            #pragma unroll
            for (int j = 0; j < 8; ++j) {
                const int fl = 4 * g + (j & 3) + 16 * (j >> 2);
                v[j] = to_bf16(W2[c * FFN + cc * 32 + fl]);
            }
        }
    }
    union { ushort s[8]; uint4 q; } pk;
    #pragma unroll
    for (int j = 0; j < 8; ++j) pk.s[j] = v[j];
    ws[idx] = pk.q;
}

// ---------------- main ----------------
__global__ __launch_bounds__(256) void tbq_mfma(
    const float* __restrict__ x,
    const float* __restrict__ Wq,
    const float* __restrict__ Wo,
    const float* __restrict__ b2,
    const float* __restrict__ g1,
    const float* __restrict__ beta1,
    const float* __restrict__ g2,
    const float* __restrict__ beta2,
    const uint4* __restrict__ ws,
    float* __restrict__ out)
{
    __shared__ __align__(16) float oS[256 * 8];   // 8KB: m-scatter (first 4KB), then epilogue

    const int tid  = threadIdx.x;
    const int lane = tid & 63;
    const int wv   = tid >> 6;
    const int c    = lane & 15;
    const int g    = lane >> 4;

    // ---- per-lane prefix: token t ----
    const int t = blockIdx.x * 256 + tid;
    const float4* xr = (const float4*)(x + (size_t)t * 8);
    float4 xa = xr[0], xb = xr[1];
    float xv[8] = {xa.x, xa.y, xa.z, xa.w, xb.x, xb.y, xb.z, xb.w};

    float qm[8];
    {
        float cp = 1.0f;
        #pragma unroll
        for (int f = 0; f < 8; ++f) {
            float acc = 0.0f;
            #pragma unroll
            for (int e = 0; e < 8; ++e) acc += xv[e] * Wq[f * 8 + e];
            cp *= __cosf(acc);
            qm[f] = cp;
        }
    }
    float h[8];
    float mu = 0.0f;
    #pragma unroll
    for (int f = 0; f < 8; ++f) {
        float acc = 0.0f;
        #pragma unroll
        for (int e = 0; e < 8; ++e) acc += qm[e] * Wo[f * 8 + e];
        h[f] = xv[f] + acc;
        mu += h[f];
    }
    mu *= 0.125f;
    float var = 0.0f;
    #pragma unroll
    for (int i = 0; i < 8; ++i) { float d = h[i] - mu; var += d * d; }
    var *= 0.125f;
    float rs = rsqrtf(var + LN_EPS);
    #pragma unroll
    for (int i = 0; i < 8; ++i) h[i] = (h[i] - mu) * rs * g1[i] + beta1[i];

    float m[8];
    {
        float cp = 1.0f;
        #pragma unroll
        for (int i = 0; i < 8; ++i) { cp *= __cosf(h[i]); m[i] = cp; }
    }

    // ---- scatter m (bf16) and gather B1 fragments (m^T with ones-row at k=8) ----
    {
        uint4 mq;
        mq.x = cvtpk(m[0], m[1]); mq.y = cvtpk(m[2], m[3]);
        mq.z = cvtpk(m[4], m[5]); mq.w = cvtpk(m[6], m[7]);
        ((uint4*)oS)[tid] = mq;
    }
    asm volatile("s_waitcnt lgkmcnt(0)" ::: "memory");

    FragU B1[4];
    #pragma unroll
    for (int T = 0; T < 4; ++T) {
        uint4 mr = ((const uint4*)oS)[wv * 64 + T * 16 + c];
        B1[T].u[0] = (g == 0) ? mr.x : ((g == 1) ? 0x00003F80u : 0u);
        B1[T].u[1] = (g == 0) ? mr.y : 0u;
        B1[T].u[2] = (g == 0) ? mr.z : 0u;
        B1[T].u[3] = (g == 0) ? mr.w : 0u;
    }
    __syncthreads();   // oS m-region may overlap another wave's epilogue region

    // ---- fused FFN: 64 chunks of 32 f, fragments pre-baked in ws (zero build VALU) ----
    const uint4* fw1 = ws + lane;          // [cc*128 (+64 for s=1)]
    const uint4* fw2 = ws + 8192 + lane;   // [cc*64]

    f32x4 acc[4] = {{0,0,0,0},{0,0,0,0},{0,0,0,0},{0,0,0,0}};

    #pragma unroll 2
    for (int cc = 0; cc < 64; ++cc) {
        FragU F0, F1, A2;
        F0.q = fw1[cc * 128];
        F1.q = fw1[cc * 128 + 64];
        A2.q = fw2[cc * 64];

        #pragma unroll
        for (int T = 0; T < 4; ++T) {
            f32x4 z = {0, 0, 0, 0};
            f32x4 c0 = __builtin_amdgcn_mfma_f32_16x16x32_bf16(F0.v, B1[T].v, z, 0, 0, 0);
            f32x4 c1 = __builtin_amdgcn_mfma_f32_16x16x32_bf16(F1.v, B1[T].v, z, 0, 0, 0);
            FragU B2;
            B2.u[0] = cvtpk(fmaxf(c0[0], 0.f), fmaxf(c0[1], 0.f));
            B2.u[1] = cvtpk(fmaxf(c0[2], 0.f), fmaxf(c0[3], 0.f));
            B2.u[2] = cvtpk(fmaxf(c1[0], 0.f), fmaxf(c1[1], 0.f));
            B2.u[3] = cvtpk(fmaxf(c1[2], 0.f), fmaxf(c1[3], 0.f));
            acc[T] = __builtin_amdgcn_mfma_f32_16x16x32_bf16(A2.v, B2.v, acc[T], 0, 0, 0);
        }
    }

    // ---- epilogue: acc frags -> oS, per-lane LN2, store ----
    if (g < 2) {
        #pragma unroll
        for (int T = 0; T < 4; ++T) {
            int tok = wv * 64 + T * 16 + c;
            *(f32x4*)&oS[tok * 8 + 4 * g] = acc[T];
        }
    }
    asm volatile("s_waitcnt lgkmcnt(0)" ::: "memory");

    f32x4 p0 = ((const f32x4*)oS)[tid * 2];
    f32x4 p1 = ((const f32x4*)oS)[tid * 2 + 1];
    float ffnv[8] = {p0[0], p0[1], p0[2], p0[3], p1[0], p1[1], p1[2], p1[3]};

    float o[8];
    float mu2 = 0.0f;
    #pragma unroll
    for (int i = 0; i < 8; ++i) { o[i] = h[i] + ffnv[i] + b2[i]; mu2 += o[i]; }
    mu2 *= 0.125f;
    float v2 = 0.0f;
    #pragma unroll
    for (int i = 0; i < 8; ++i) { float d = o[i] - mu2; v2 += d * d; }
    v2 *= 0.125f;
    float rs2 = rsqrtf(v2 + LN_EPS);

    float res[8];
    #pragma unroll
    for (int i = 0; i < 8; ++i) res[i] = (o[i] - mu2) * rs2 * g2[i] + beta2[i];

    float4* orow = (float4*)(out + (size_t)t * 8);
    orow[0] = make_float4(res[0], res[1], res[2], res[3]);
    orow[1] = make_float4(res[4], res[5], res[6], res[7]);
}

extern "C" void kernel_launch(void* const* d_in, const int* in_sizes, int n_in,
                              void* d_out, int out_size, void* d_ws, size_t ws_size,
                              hipStream_t stream) {
    const float* x     = (const float*)d_in[0];
    const float* Wq    = (const float*)d_in[1];
    const float* Wo    = (const float*)d_in[2];
    const float* W1    = (const float*)d_in[3];
    const float* b1    = (const float*)d_in[4];
    const float* W2    = (const float*)d_in[5];
    const float* b2    = (const float*)d_in[6];
    const float* g1    = (const float*)d_in[7];
    const float* beta1 = (const float*)d_in[8];
    const float* g2    = (const float*)d_in[9];
    const float* beta2 = (const float*)d_in[10];
    float* out = (float*)d_out;
    uint4* ws = (uint4*)d_ws;   // needs 12288*16 = 192 KiB

    tbq_prep<<<48, 256, 0, stream>>>(W1, b1, W2, ws);

    const int ntok = in_sizes[0] / 8;      // 131072
    const int grid = ntok / 256;           // 512 blocks x 4 waves x 64 tok
    tbq_mfma<<<grid, 256, 0, stream>>>(x, Wq, Wo, b2, g1, beta1, g2, beta2, ws, out);
}

// Round 5
// 42.899 us; speedup vs baseline: 4.6368x; 1.2177x over previous
//
#include <hip/hip_runtime.h>
#include <hip/hip_bf16.h>

#define FFN 2048
#define LN_EPS 1e-5f

typedef __attribute__((ext_vector_type(8))) short bf16x8;
typedef __attribute__((ext_vector_type(4))) float f32x4;

union FragU { bf16x8 v; unsigned u[4]; uint4 q; };

static __device__ __forceinline__ unsigned cvtpk(float lo, float hi) {
    unsigned r;
    asm("v_cvt_pk_bf16_f32 %0, %1, %2" : "=v"(r) : "v"(lo), "v"(hi));
    return r;
}

static __device__ __forceinline__ ushort to_bf16(float f) {   // RNE, finite inputs
    unsigned u = __float_as_uint(f);
    u += 0x7fffu + ((u >> 16) & 1u);
    return (ushort)(u >> 16);
}

// ---------------- prep: bake exact per-lane MFMA fragments into ws ----------------
// ws uint4 layout: [0..8191]  fragW1[cc][s][lane]  (A-frag of W1aug: k=8g+j, k<8 -> W1[f][k],
//                                                   k==8 -> b1[f], else 0; f = cc*32+s*16+c)
//                  [8192..12287] fragW2[cc][lane]  (A-frag of W2, permuted k: lane(c,g), j ->
//                                                   f_local = 4g + (j&3) + 16*(j>>2); rows c>=8 zero)
__global__ __launch_bounds__(256) void tbq_prep(
    const float* __restrict__ W1, const float* __restrict__ b1,
    const float* __restrict__ W2, uint4* __restrict__ ws)
{
    const int idx = blockIdx.x * 256 + threadIdx.x;
    ushort v[8] = {0,0,0,0,0,0,0,0};
    if (idx < 8192) {
        const int lane = idx & 63, s = (idx >> 6) & 1, cc = idx >> 7;
        const int c = lane & 15, g = lane >> 4;
        const int f = cc * 32 + s * 16 + c;
        if (g == 0) {
            #pragma unroll
            for (int j = 0; j < 8; ++j) v[j] = to_bf16(W1[f * 8 + j]);
        } else if (g == 1) {
            v[0] = to_bf16(b1[f]);
        }
    } else {
        const int i2 = idx - 8192;
        const int lane = i2 & 63, cc = i2 >> 6;
        const int c = lane & 15, g = lane >> 4;
        if (c < 8) {
            #pragma unroll
            for (int j = 0; j < 8; ++j) {
                const int fl = 4 * g + (j & 3) + 16 * (j >> 2);
                v[j] = to_bf16(W2[c * FFN + cc * 32 + fl]);
            }
        }
    }
    union { ushort s[8]; uint4 q; } pk;
    #pragma unroll
    for (int j = 0; j < 8; ++j) pk.s[j] = v[j];
    ws[idx] = pk.q;
}

// ---------------- main: 64 tokens/block, 4 waves split the f-dimension ----------------
__global__ __launch_bounds__(256, 6) void tbq_mfma(
    const float* __restrict__ x,
    const float* __restrict__ Wq,
    const float* __restrict__ Wo,
    const float* __restrict__ b2,
    const float* __restrict__ g1,
    const float* __restrict__ beta1,
    const float* __restrict__ g2,
    const float* __restrict__ beta2,
    const uint4* __restrict__ ws,
    float* __restrict__ out)
{
    __shared__ __align__(16) uint4 mS[64];           // 1KB  m (bf16) per token
    __shared__ __align__(16) float part[4][64][8];   // 8KB  per-wave partial ffn

    const int tid  = threadIdx.x;
    const int lane = tid & 63;
    const int wv   = tid >> 6;
    const int c    = lane & 15;
    const int g    = lane >> 4;

    // ---- prefix for token t = blk*64 + lane (duplicated across the 4 waves) ----
    const int t = blockIdx.x * 64 + lane;
    const float4* xr = (const float4*)(x + (size_t)t * 8);
    float4 xa = xr[0], xb = xr[1];
    float xv[8] = {xa.x, xa.y, xa.z, xa.w, xb.x, xb.y, xb.z, xb.w};

    float qm[8];
    {
        float cp = 1.0f;
        #pragma unroll
        for (int f = 0; f < 8; ++f) {
            float acc = 0.0f;
            #pragma unroll
            for (int e = 0; e < 8; ++e) acc += xv[e] * Wq[f * 8 + e];
            cp *= __cosf(acc);
            qm[f] = cp;
        }
    }
    float h[8];
    float mu = 0.0f;
    #pragma unroll
    for (int f = 0; f < 8; ++f) {
        float acc = 0.0f;
        #pragma unroll
        for (int e = 0; e < 8; ++e) acc += qm[e] * Wo[f * 8 + e];
        h[f] = xv[f] + acc;
        mu += h[f];
    }
    mu *= 0.125f;
    float var = 0.0f;
    #pragma unroll
    for (int i = 0; i < 8; ++i) { float d = h[i] - mu; var += d * d; }
    var *= 0.125f;
    float rs = rsqrtf(var + LN_EPS);
    #pragma unroll
    for (int i = 0; i < 8; ++i) h[i] = (h[i] - mu) * rs * g1[i] + beta1[i];

    float m[8];
    {
        float cp = 1.0f;
        #pragma unroll
        for (int i = 0; i < 8; ++i) { cp *= __cosf(h[i]); m[i] = cp; }
    }

    // ---- wave 0 scatters m (bf16) for the block's 64 tokens ----
    if (wv == 0) {
        uint4 mq;
        mq.x = cvtpk(m[0], m[1]); mq.y = cvtpk(m[2], m[3]);
        mq.z = cvtpk(m[4], m[5]); mq.w = cvtpk(m[6], m[7]);
        mS[lane] = mq;
    }
    __syncthreads();

    // ---- every wave gathers B1 fragments for the same 64 tokens ----
    FragU B1[4];
    #pragma unroll
    for (int T = 0; T < 4; ++T) {
        uint4 mr = mS[T * 16 + c];
        B1[T].u[0] = (g == 0) ? mr.x : ((g == 1) ? 0x00003F80u : 0u);  // k=8 row: 1.0
        B1[T].u[1] = (g == 0) ? mr.y : 0u;
        B1[T].u[2] = (g == 0) ? mr.z : 0u;
        B1[T].u[3] = (g == 0) ? mr.w : 0u;
    }

    // ---- FFN: this wave's 16 chunks (f in [wv*512, wv*512+512)) ----
    const uint4* fw1 = ws + lane;
    const uint4* fw2 = ws + 8192 + lane;

    f32x4 acc[4] = {{0,0,0,0},{0,0,0,0},{0,0,0,0},{0,0,0,0}};

    #pragma unroll 4
    for (int i = 0; i < 16; ++i) {
        const int cc = wv * 16 + i;
        FragU F0, F1, A2;
        F0.q = fw1[cc * 128];
        F1.q = fw1[cc * 128 + 64];
        A2.q = fw2[cc * 64];

        #pragma unroll
        for (int T = 0; T < 4; ++T) {
            f32x4 z = {0, 0, 0, 0};
            f32x4 c0 = __builtin_amdgcn_mfma_f32_16x16x32_bf16(F0.v, B1[T].v, z, 0, 0, 0);
            f32x4 c1 = __builtin_amdgcn_mfma_f32_16x16x32_bf16(F1.v, B1[T].v, z, 0, 0, 0);
            FragU B2;
            B2.u[0] = cvtpk(fmaxf(c0[0], 0.f), fmaxf(c0[1], 0.f));
            B2.u[1] = cvtpk(fmaxf(c0[2], 0.f), fmaxf(c0[3], 0.f));
            B2.u[2] = cvtpk(fmaxf(c1[0], 0.f), fmaxf(c1[1], 0.f));
            B2.u[3] = cvtpk(fmaxf(c1[2], 0.f), fmaxf(c1[3], 0.f));
            acc[T] = __builtin_amdgcn_mfma_f32_16x16x32_bf16(A2.v, B2.v, acc[T], 0, 0, 0);
        }
    }

    // ---- write partial fragments: part[wv][tok][e] ----
    if (g < 2) {
        #pragma unroll
        for (int T = 0; T < 4; ++T) {
            *(f32x4*)&part[wv][T * 16 + c][4 * g] = acc[T];
        }
    }
    __syncthreads();

    // ---- wave 0 reduces + LN2 + store (token = lane, h already in registers) ----
    if (wv == 0) {
        float ffnv[8];
        #pragma unroll
        for (int e = 0; e < 8; ++e)
            ffnv[e] = part[0][lane][e] + part[1][lane][e]
                    + part[2][lane][e] + part[3][lane][e];

        float o[8];
        float mu2 = 0.0f;
        #pragma unroll
        for (int i = 0; i < 8; ++i) { o[i] = h[i] + ffnv[i] + b2[i]; mu2 += o[i]; }
        mu2 *= 0.125f;
        float v2 = 0.0f;
        #pragma unroll
        for (int i = 0; i < 8; ++i) { float d = o[i] - mu2; v2 += d * d; }
        v2 *= 0.125f;
        float rs2 = rsqrtf(v2 + LN_EPS);

        float res[8];
        #pragma unroll
        for (int i = 0; i < 8; ++i) res[i] = (o[i] - mu2) * rs2 * g2[i] + beta2[i];

        float4* orow = (float4*)(out + (size_t)t * 8);
        orow[0] = make_float4(res[0], res[1], res[2], res[3]);
        orow[1] = make_float4(res[4], res[5], res[6], res[7]);
    }
}

extern "C" void kernel_launch(void* const* d_in, const int* in_sizes, int n_in,
                              void* d_out, int out_size, void* d_ws, size_t ws_size,
                              hipStream_t stream) {
    const float* x     = (const float*)d_in[0];
    const float* Wq    = (const float*)d_in[1];
    const float* Wo    = (const float*)d_in[2];
    const float* W1    = (const float*)d_in[3];
    const float* b1    = (const float*)d_in[4];
    const float* W2    = (const float*)d_in[5];
    const float* b2    = (const float*)d_in[6];
    const float* g1    = (const float*)d_in[7];
    const float* beta1 = (const float*)d_in[8];
    const float* g2    = (const float*)d_in[9];
    const float* beta2 = (const float*)d_in[10];
    float* out = (float*)d_out;
    uint4* ws = (uint4*)d_ws;   // needs 12288*16 = 192 KiB

    tbq_prep<<<48, 256, 0, stream>>>(W1, b1, W2, ws);

    const int ntok = in_sizes[0] / 8;      // 131072
    const int grid = ntok / 64;            // 2048 blocks, 4 waves f-split
    tbq_mfma<<<grid, 256, 0, stream>>>(x, Wq, Wo, b2, g1, beta1, g2, beta2, ws, out);
}

// Round 6
// 37.224 us; speedup vs baseline: 5.3436x; 1.1524x over previous
//
#include <hip/hip_runtime.h>
#include <hip/hip_bf16.h>

#define FFN 2048
#define LN_EPS 1e-5f

typedef __attribute__((ext_vector_type(8))) short bf16x8;
typedef __attribute__((ext_vector_type(4))) float f32x4;

union FragU { bf16x8 v; unsigned u[4]; uint4 q; };

static __device__ __forceinline__ unsigned cvtpk(float lo, float hi) {
    unsigned r;
    asm("v_cvt_pk_bf16_f32 %0, %1, %2" : "=v"(r) : "v"(lo), "v"(hi));
    return r;
}

// relu on a packed bf16 pair: sign bit position matches f16; |x| << 2^121 so no
// f16-NaN aliasing -> v_pk_max_f16(v, 0) zeroes negative halves exactly.
static __device__ __forceinline__ unsigned pkrelu(unsigned a, unsigned z) {
    unsigned r;
    asm("v_pk_max_f16 %0, %1, %2" : "=v"(r) : "v"(a), "v"(z));
    return r;
}

static __device__ __forceinline__ ushort to_bf16(float f) {   // RNE, finite inputs
    unsigned u = __float_as_uint(f);
    u += 0x7fffu + ((u >> 16) & 1u);
    return (ushort)(u >> 16);
}

// ---------------- prep: bake exact per-lane MFMA fragments into ws ----------------
// ws uint4 layout: [0..8191]  fragW1[cc][s][lane]  (A-frag of W1aug: k=8g+j, k<8 -> W1[f][k],
//                                                   k==8 -> b1[f], else 0; f = cc*32+s*16+c)
//                  [8192..12287] fragW2[cc][lane]  (A-frag of W2, permuted k: lane(c,g), j ->
//                                                   f_local = 4g + (j&3) + 16*(j>>2); rows c>=8 zero)
__global__ __launch_bounds__(256) void tbq_prep(
    const float* __restrict__ W1, const float* __restrict__ b1,
    const float* __restrict__ W2, uint4* __restrict__ ws)
{
    const int idx = blockIdx.x * 256 + threadIdx.x;
    ushort v[8] = {0,0,0,0,0,0,0,0};
    if (idx < 8192) {
        const int lane = idx & 63, s = (idx >> 6) & 1, cc = idx >> 7;
        const int c = lane & 15, g = lane >> 4;
        const int f = cc * 32 + s * 16 + c;
        if (g == 0) {
            #pragma unroll
            for (int j = 0; j < 8; ++j) v[j] = to_bf16(W1[f * 8 + j]);
        } else if (g == 1) {
            v[0] = to_bf16(b1[f]);
        }
    } else {
        const int i2 = idx - 8192;
        const int lane = i2 & 63, cc = i2 >> 6;
        const int c = lane & 15, g = lane >> 4;
        if (c < 8) {
            #pragma unroll
            for (int j = 0; j < 8; ++j) {
                const int fl = 4 * g + (j & 3) + 16 * (j >> 2);
                v[j] = to_bf16(W2[c * FFN + cc * 32 + fl]);
            }
        }
    }
    union { ushort s[8]; uint4 q; } pk;
    #pragma unroll
    for (int j = 0; j < 8; ++j) pk.s[j] = v[j];
    ws[idx] = pk.q;
}

// ---------------- main: 64 tokens/block, 4 waves f-split, wave0-only prefix ----------------
__global__ __launch_bounds__(256) void tbq_mfma(
    const float* __restrict__ x,
    const float* __restrict__ Wq,
    const float* __restrict__ Wo,
    const float* __restrict__ b2,
    const float* __restrict__ g1,
    const float* __restrict__ beta1,
    const float* __restrict__ g2,
    const float* __restrict__ beta2,
    const uint4* __restrict__ ws,
    float* __restrict__ out)
{
    __shared__ __align__(16) uint4 mS[64];           // 1KB  m (bf16) per token
    __shared__ __align__(16) float part[4][64][8];   // 8KB  per-wave partial ffn

    const int tid  = threadIdx.x;
    const int lane = tid & 63;
    const int wv   = tid >> 6;
    const int c    = lane & 15;
    const int g    = lane >> 4;
    const int t    = blockIdx.x * 64 + lane;

    const uint4* fw1 = ws + lane;
    const uint4* fw2 = ws + 8192 + lane;
    const int cc0 = wv * 16;

    // ---- prefetch chunk 0 fragments (issues before the barrier; hides under prefix) ----
    FragU F0[2], F1[2], A2[2];
    F0[0].q = fw1[cc0 * 128];
    F1[0].q = fw1[cc0 * 128 + 64];
    A2[0].q = fw2[cc0 * 64];

    // ---- wave 0 only: per-token prefix (lane = token) ----
    float h[8];
    if (wv == 0) {
        const float4* xr = (const float4*)(x + (size_t)t * 8);
        float4 xa = xr[0], xb = xr[1];
        float xv[8] = {xa.x, xa.y, xa.z, xa.w, xb.x, xb.y, xb.z, xb.w};

        float qm[8];
        {
            float cp = 1.0f;
            #pragma unroll
            for (int f = 0; f < 8; ++f) {
                float acc = 0.0f;
                #pragma unroll
                for (int e = 0; e < 8; ++e) acc += xv[e] * Wq[f * 8 + e];
                cp *= __cosf(acc);
                qm[f] = cp;
            }
        }
        float mu = 0.0f;
        #pragma unroll
        for (int f = 0; f < 8; ++f) {
            float acc = 0.0f;
            #pragma unroll
            for (int e = 0; e < 8; ++e) acc += qm[e] * Wo[f * 8 + e];
            h[f] = xv[f] + acc;
            mu += h[f];
        }
        mu *= 0.125f;
        float var = 0.0f;
        #pragma unroll
        for (int i = 0; i < 8; ++i) { float d = h[i] - mu; var += d * d; }
        var *= 0.125f;
        float rs = rsqrtf(var + LN_EPS);
        #pragma unroll
        for (int i = 0; i < 8; ++i) h[i] = (h[i] - mu) * rs * g1[i] + beta1[i];

        float m[8];
        {
            float cp = 1.0f;
            #pragma unroll
            for (int i = 0; i < 8; ++i) { cp *= __cosf(h[i]); m[i] = cp; }
        }
        uint4 mq;
        mq.x = cvtpk(m[0], m[1]); mq.y = cvtpk(m[2], m[3]);
        mq.z = cvtpk(m[4], m[5]); mq.w = cvtpk(m[6], m[7]);
        mS[lane] = mq;
    }
    __syncthreads();

    // ---- every wave gathers B1 fragments (m^T with ones-row at k=8) ----
    FragU B1[4];
    #pragma unroll
    for (int T = 0; T < 4; ++T) {
        uint4 mr = mS[T * 16 + c];
        B1[T].u[0] = (g == 0) ? mr.x : ((g == 1) ? 0x00003F80u : 0u);
        B1[T].u[1] = (g == 0) ? mr.y : 0u;
        B1[T].u[2] = (g == 0) ? mr.z : 0u;
        B1[T].u[3] = (g == 0) ? mr.w : 0u;
    }

    // ---- FFN: 16 chunks, 2-deep pipelined fragment loads ----
    f32x4 acc[4] = {{0,0,0,0},{0,0,0,0},{0,0,0,0},{0,0,0,0}};
    const unsigned zz = 0u;

    #pragma unroll
    for (int i = 0; i < 16; ++i) {
        const int cur = i & 1, nxt = cur ^ 1;
        if (i < 15) {
            F0[nxt].q = fw1[(cc0 + i + 1) * 128];
            F1[nxt].q = fw1[(cc0 + i + 1) * 128 + 64];
            A2[nxt].q = fw2[(cc0 + i + 1) * 64];
        }
        #pragma unroll
        for (int T = 0; T < 4; ++T) {
            f32x4 z = {0, 0, 0, 0};
            f32x4 c0 = __builtin_amdgcn_mfma_f32_16x16x32_bf16(F0[cur].v, B1[T].v, z, 0, 0, 0);
            f32x4 c1 = __builtin_amdgcn_mfma_f32_16x16x32_bf16(F1[cur].v, B1[T].v, z, 0, 0, 0);
            FragU B2;
            B2.u[0] = pkrelu(cvtpk(c0[0], c0[1]), zz);
            B2.u[1] = pkrelu(cvtpk(c0[2], c0[3]), zz);
            B2.u[2] = pkrelu(cvtpk(c1[0], c1[1]), zz);
            B2.u[3] = pkrelu(cvtpk(c1[2], c1[3]), zz);
            acc[T] = __builtin_amdgcn_mfma_f32_16x16x32_bf16(A2[cur].v, B2.v, acc[T], 0, 0, 0);
        }
    }

    // ---- write partial fragments: part[wv][tok][e] ----
    if (g < 2) {
        #pragma unroll
        for (int T = 0; T < 4; ++T) {
            *(f32x4*)&part[wv][T * 16 + c][4 * g] = acc[T];
        }
    }
    __syncthreads();

    // ---- wave 0 reduces + LN2 + store (token = lane, h in registers) ----
    if (wv == 0) {
        float ffnv[8];
        #pragma unroll
        for (int e = 0; e < 8; ++e)
            ffnv[e] = part[0][lane][e] + part[1][lane][e]
                    + part[2][lane][e] + part[3][lane][e];

        float o[8];
        float mu2 = 0.0f;
        #pragma unroll
        for (int i = 0; i < 8; ++i) { o[i] = h[i] + ffnv[i] + b2[i]; mu2 += o[i]; }
        mu2 *= 0.125f;
        float v2 = 0.0f;
        #pragma unroll
        for (int i = 0; i < 8; ++i) { float d = o[i] - mu2; v2 += d * d; }
        v2 *= 0.125f;
        float rs2 = rsqrtf(v2 + LN_EPS);

        float res[8];
        #pragma unroll
        for (int i = 0; i < 8; ++i) res[i] = (o[i] - mu2) * rs2 * g2[i] + beta2[i];

        float4* orow = (float4*)(out + (size_t)t * 8);
        orow[0] = make_float4(res[0], res[1], res[2], res[3]);
        orow[1] = make_float4(res[4], res[5], res[6], res[7]);
    }
}

extern "C" void kernel_launch(void* const* d_in, const int* in_sizes, int n_in,
                              void* d_out, int out_size, void* d_ws, size_t ws_size,
                              hipStream_t stream) {
    const float* x     = (const float*)d_in[0];
    const float* Wq    = (const float*)d_in[1];
    const float* Wo    = (const float*)d_in[2];
    const float* W1    = (const float*)d_in[3];
    const float* b1    = (const float*)d_in[4];
    const float* W2    = (const float*)d_in[5];
    const float* b2    = (const float*)d_in[6];
    const float* g1    = (const float*)d_in[7];
    const float* beta1 = (const float*)d_in[8];
    const float* g2    = (const float*)d_in[9];
    const float* beta2 = (const float*)d_in[10];
    float* out = (float*)d_out;
    uint4* ws = (uint4*)d_ws;   // needs 12288*16 = 192 KiB

    tbq_prep<<<48, 256, 0, stream>>>(W1, b1, W2, ws);

    const int ntok = in_sizes[0] / 8;      // 131072
    const int grid = ntok / 64;            // 2048 blocks, 4 waves f-split
    tbq_mfma<<<grid, 256, 0, stream>>>(x, Wq, Wo, b2, g1, beta1, g2, beta2, ws, out);
}